// Round 9
// baseline (281.083 us; speedup 1.0000x reference)
//
#include <hip/hip_runtime.h>

// Problem constants (reference: NUM_SAMPLES=8192, EMBED=64, TAU=0.2)
#define EMBED        64
#define NS           8192
#define NTILE        256            // 32-row tiles per matrix
#define JCHUNKS      8
#define JT_PER_CHUNK 32             // NTILE / JCHUNKS
#define NPHASE       (JT_PER_CHUNK / 2)   // 16 two-jt phases
#define NBLOCKS_MAIN (2 * 64 * JCHUNKS)   // 1024
#define C_L2E_TAU    7.21347520444482f    // INV_TAU * log2(e) = 5 / ln(2)

typedef _Float16 half8  __attribute__((ext_vector_type(8)));
typedef float    f32x16 __attribute__((ext_vector_type(16)));

// async global->LDS, 16B/lane. Global addr is per-lane; LDS base wave-uniform.
#define GLDS16(g, l) __builtin_amdgcn_global_load_lds( \
    (const __attribute__((address_space(1))) void*)(g), \
    (__attribute__((address_space(3))) void*)(l), 16, 0, 0)

// Raw v_exp_f32: D = 2^x. Input here is in [-2300, +30]: large negatives
// flush to 0 (desired), no NaN/inf path.
static __device__ __forceinline__ float exp2_raw(float x) {
  float r;
  asm("v_exp_f32 %0, %1" : "=v"(r) : "v"(x));
  return r;
}

// ---------------------------------------------------------------------------
// Prep: gather + f32->(h,l) fp16 split + diag, writing fragment-major layout
//   Efrag[mat][tile(256)][frag(8)][lane(64)][8 f16],  frag = hl*4 + ktile
// MFMA 32x32x16 fragment: lane l, elem j -> row = l&31, k = kt*16+(l>>5)*8+j
// Block = one (mat,tile); wave = one ktile; thread reads 32B of its row.
// Also zeroes the main kernel's completion counter (fresh every launch).
// ---------------------------------------------------------------------------
__global__ __launch_bounds__(256) void prep_kernel(
    const float* __restrict__ users, const float* __restrict__ items,
    const int* __restrict__ uidx, const int* __restrict__ iidx,
    _Float16* __restrict__ Efrag, float* __restrict__ diag,
    int* __restrict__ done_cnt) {
  int b = blockIdx.x;
  if (b == 0 && threadIdx.x == 0) *done_cnt = 0;
  int mat = b >> 8, tile = b & 255;
  int kt = threadIdx.x >> 6;              // wave index = k-tile
  int lane = threadIdx.x & 63;
  int r = lane & 31;                      // row within tile
  int k0 = kt * 16 + (lane >> 5) * 8;     // my 8-float slice
  int row = tile * 32 + r;
  int src = mat ? iidx[row] : uidx[row];
  const float4* basep =
      (const float4*)((mat ? items : users) + (size_t)src * EMBED + k0);
  float4 v0 = basep[0], v1 = basep[1];
  float vs[8] = {v0.x, v0.y, v0.z, v0.w, v1.x, v1.y, v1.z, v1.w};

  half8 hh, ll;
  float p = 0.f;
  #pragma unroll
  for (int j = 0; j < 8; ++j) {
    float v = vs[j];
    _Float16 h = (_Float16)v;
    hh[j] = h;
    ll[j] = (_Float16)(v - (float)h);
    p = fmaf(v, v, p);
  }
  _Float16* tb = Efrag + (size_t)(mat * NTILE + tile) * 4096;  // 8KB per tile
  *(half8*)(tb + ((kt)     * 64 + lane) * 8) = hh;   // frag kt     (high)
  *(half8*)(tb + ((4 + kt) * 64 + lane) * 8) = ll;   // frag 4+kt   (low)

  // diag = ||row||^2 : lanes l and l^32 hold the two 8-slices of ktile kt
  p += __shfl_xor(p, 32);
  __shared__ float ds[4][32];
  if (lane < 32) ds[kt][lane] = p;
  __syncthreads();
  if (threadIdx.x < 32)
    diag[mat * NS + tile * 32 + threadIdx.x] =
        ds[0][threadIdx.x] + ds[1][threadIdx.x] +
        ds[2][threadIdx.x] + ds[3][threadIdx.x];
}

// ---------------------------------------------------------------------------
// Main v5: LDS-fed B (R5-proven skeleton) with 2-jt phases (half the
// barriers; stage drained a full ~1000-cyc phase later), 3-chain MFMA ILP
// (R8-proven), negdv C-init (R5-proven). 4 waves/block, 4 blocks/CU,
// 16 waves/CU. Finalize fused via last-block ticket.
// Grid = 2 mats x 64 rowgroups x 8 jchunks = 1024 blocks.
// ---------------------------------------------------------------------------
__global__ __launch_bounds__(256, 4) void ssm_mfma_kernel(
    const _Float16* __restrict__ Efrag, const float* __restrict__ diag,
    float* __restrict__ rowpart, int* __restrict__ done_cnt,
    float* __restrict__ out) {
  int b = blockIdx.x;
  int jc  = b & (JCHUNKS - 1);
  int sg  = (b >> 3) & 63;
  int mat = b >> 9;
  int wave = threadIdx.x >> 6;
  int lane = threadIdx.x & 63;
  int hf   = lane >> 5;

  int rowtile = sg * 4 + wave;        // 0..255
  const _Float16* Em = Efrag + (size_t)mat * NTILE * 4096;

  // A fragments (frags 0..3 = h ktiles, 4..7 = l ktiles)
  half8 a[8];
  #pragma unroll
  for (int f = 0; f < 8; ++f)
    a[f] = *(const half8*)(Em + (size_t)rowtile * 4096 + (f * 64 + lane) * 8);

  // negdv = -diag (C slot r -> local row (r&3)+8*(r>>2)+4*hf)
  float negdv[16];
  #pragma unroll
  for (int r = 0; r < 16; ++r)
    negdv[r] = -diag[mat * NS + rowtile * 32 + (r & 3) + 8 * (r >> 2) + 4 * hf];

  float rs[16];
  #pragma unroll
  for (int r = 0; r < 16; ++r) rs[r] = 0.f;

  __shared__ __align__(16) _Float16 Bbuf[2][8192];   // 2 x 16KB (two jt each)

  int tj0 = jc * JT_PER_CHUNK;
  // stage one 16KB pair of consecutive j-tiles into Bbuf[buf]
  auto stage = [&](int buf, int pair) {
    const char* src = (const char*)(Em + (size_t)(tj0 + 2 * pair) * 4096);
    char* dst = (char*)&Bbuf[buf][0];
    int o = wave * 4096;
    #pragma unroll
    for (int q = 0; q < 4; ++q)
      GLDS16(src + o + q * 1024 + lane * 16, dst + o + q * 1024);
  };

  // one j-tile: 8 ds_read_b128 + 12 MFMA as 3 interleaved 4-link chains
  auto compute = [&](const _Float16* B) {
    f32x16 c0, c1, c2;
    #pragma unroll
    for (int r = 0; r < 16; ++r) { c0[r] = negdv[r]; c1[r] = 0.f; c2[r] = 0.f; }
    #pragma unroll
    for (int k = 0; k < 4; ++k) {
      half8 bh = *(const half8*)(B + ((k)     * 64 + lane) * 8);
      half8 bl = *(const half8*)(B + ((4 + k) * 64 + lane) * 8);
      c0 = __builtin_amdgcn_mfma_f32_32x32x16_f16(a[k],     bh, c0, 0, 0, 0); // h*h (+ -d)
      c1 = __builtin_amdgcn_mfma_f32_32x32x16_f16(a[k],     bl, c1, 0, 0, 0); // h*l
      c2 = __builtin_amdgcn_mfma_f32_32x32x16_f16(a[4 + k], bh, c2, 0, 0, 0); // l*h
    }
    f32x16 s = (c0 + c1) + c2;          // includes -d_i
    #pragma unroll
    for (int r = 0; r < 16; ++r)
      rs[r] += exp2_raw(s[r] * C_L2E_TAU);
  };

  stage(0, 0);
  __syncthreads();   // drains vmcnt before first use

  for (int p = 0; p < NPHASE; ++p) {
    if (p + 1 < NPHASE) stage((p + 1) & 1, p + 1);  // into the other buffer
    const _Float16* B = &Bbuf[p & 1][0];
    compute(B);          // jt = 2p
    compute(B + 4096);   // jt = 2p+1
    __syncthreads();     // all reads of Bbuf[p&1] done; next stage may overwrite
  }

  // reduce row partials across the 32 lanes of each half, store per chunk
  #pragma unroll
  for (int r = 0; r < 16; ++r) {
    float v = rs[r];
    #pragma unroll
    for (int off = 16; off; off >>= 1) v += __shfl_xor(v, off);
    if ((lane & 31) == 0)
      rowpart[jc * (2 * NS) + mat * NS + rowtile * 32 +
              (r & 3) + 8 * (r >> 2) + 4 * hf] = v;
  }

  // ---- fused finalize: last block to finish does the reduction ----
  __shared__ int sticket;
  __threadfence();                       // make rowpart writes visible
  if (threadIdx.x == 0) sticket = atomicAdd(done_cnt, 1);
  __syncthreads();
  if (sticket == NBLOCKS_MAIN - 1) {
    __threadfence();                     // acquire: see all rowpart writes
    float lu = 0.f, li = 0.f;
    for (int r = threadIdx.x; r < 2 * NS; r += 256) {
      float s = 0.f;
      #pragma unroll
      for (int c = 0; c < JCHUNKS; ++c) s += rowpart[c * (2 * NS) + r];
      float l = logf(s);
      if (r < NS) lu += l; else li += l;
    }
    #pragma unroll
    for (int off = 32; off; off >>= 1) {
      lu += __shfl_down(lu, off);
      li += __shfl_down(li, off);
    }
    __shared__ float red[2][4];
    if ((threadIdx.x & 63) == 0) {
      red[0][threadIdx.x >> 6] = lu;
      red[1][threadIdx.x >> 6] = li;
    }
    __syncthreads();
    if (threadIdx.x == 0) {
      float su = (red[0][0] + red[0][1] + red[0][2] + red[0][3]) * (1.0f / NS);
      float si = (red[1][0] + red[1][1] + red[1][2] + red[1][3]) * (1.0f / NS);
      out[0] = su + si;
      out[1] = su;
      out[2] = si;
    }
  }
}

// ---------------------------------------------------------------------------
// ws: Efrag 4MB | diag 64KB | rowpart 512KB | done_cnt 4B  (~4.57MB total,
// within the footprint proven since R1). done_cnt zeroed by prep each launch.
// ---------------------------------------------------------------------------
extern "C" void kernel_launch(void* const* d_in, const int* in_sizes, int n_in,
                              void* d_out, int out_size, void* d_ws, size_t ws_size,
                              hipStream_t stream) {
  const float* users = (const float*)d_in[0];
  const float* items = (const float*)d_in[1];
  const int*   uidx  = (const int*)d_in[2];
  const int*   iidx  = (const int*)d_in[3];
  float* out = (float*)d_out;

  _Float16* Efrag = (_Float16*)d_ws;                         // 2*256*4096 f16 = 4MB
  float* diag     = (float*)((char*)d_ws + (size_t)4194304); // 16384 f32
  float* rowpart  = diag + 2 * NS;                           // 8*16384 f32
  int* done_cnt   = (int*)(rowpart + JCHUNKS * 2 * NS);      // 1 int

  prep_kernel<<<2 * NTILE, 256, 0, stream>>>(users, items, uidx, iidx,
                                             Efrag, diag, done_cnt);
  ssm_mfma_kernel<<<NBLOCKS_MAIN, 256, 0, stream>>>(Efrag, diag, rowpart,
                                                    done_cnt, out);
}

// Round 10
// 161.080 us; speedup vs baseline: 1.7450x; 1.7450x over previous
//
#include <hip/hip_runtime.h>

// Problem constants (reference: NUM_SAMPLES=8192, EMBED=64, TAU=0.2)
#define EMBED        64
#define NS           8192
#define NTILE        256            // 32-row tiles per matrix
#define NJC          16             // J-chunks of 16 tiles each
#define JT_PER_CHUNK 16
#define C_L2E_TAU    7.21347520444482f    // INV_TAU * log2(e) = 5 / ln(2)

typedef _Float16 half8  __attribute__((ext_vector_type(8)));
typedef float    f32x16 __attribute__((ext_vector_type(16)));

// async global->LDS, 16B/lane. Global addr is per-lane; LDS base wave-uniform.
#define GLDS16(g, l) __builtin_amdgcn_global_load_lds( \
    (const __attribute__((address_space(1))) void*)(g), \
    (__attribute__((address_space(3))) void*)(l), 16, 0, 0)

// Raw v_exp_f32: D = 2^x. Input here is in [-2300, +30]: large negatives
// flush to 0 (desired), no NaN/inf path.
static __device__ __forceinline__ float exp2_raw(float x) {
  float r;
  asm("v_exp_f32 %0, %1" : "=v"(r) : "v"(x));
  return r;
}

// ---------------------------------------------------------------------------
// Prep: gather + f32->(h,l) fp16 split + diag, writing fragment-major layout
//   Efrag[mat][tile(256)][frag(8)][lane(64)][8 f16],  frag = hl*4 + ktile
// MFMA 32x32x16 fragment: lane l, elem j -> row = l&31, k = kt*16+(l>>5)*8+j
// Block = one (mat,tile); wave = one ktile; thread reads 32B of its row.
// Also zeroes this (mat,tile)'s 32 accum slots (atomic targets for main).
// ---------------------------------------------------------------------------
__global__ __launch_bounds__(256) void prep_kernel(
    const float* __restrict__ users, const float* __restrict__ items,
    const int* __restrict__ uidx, const int* __restrict__ iidx,
    _Float16* __restrict__ Efrag, float* __restrict__ diag,
    float* __restrict__ accum) {
  int b = blockIdx.x;
  int mat = b >> 8, tile = b & 255;
  if (threadIdx.x < 32) accum[mat * NS + tile * 32 + threadIdx.x] = 0.f;
  int kt = threadIdx.x >> 6;              // wave index = k-tile
  int lane = threadIdx.x & 63;
  int r = lane & 31;                      // row within tile
  int k0 = kt * 16 + (lane >> 5) * 8;     // my 8-float slice
  int row = tile * 32 + r;
  int src = mat ? iidx[row] : uidx[row];
  const float4* basep =
      (const float4*)((mat ? items : users) + (size_t)src * EMBED + k0);
  float4 v0 = basep[0], v1 = basep[1];
  float vs[8] = {v0.x, v0.y, v0.z, v0.w, v1.x, v1.y, v1.z, v1.w};

  half8 hh, ll;
  float p = 0.f;
  #pragma unroll
  for (int j = 0; j < 8; ++j) {
    float v = vs[j];
    _Float16 h = (_Float16)v;
    hh[j] = h;
    ll[j] = (_Float16)(v - (float)h);
    p = fmaf(v, v, p);
  }
  _Float16* tb = Efrag + (size_t)(mat * NTILE + tile) * 4096;  // 8KB per tile
  *(half8*)(tb + ((kt)     * 64 + lane) * 8) = hh;   // frag kt     (high)
  *(half8*)(tb + ((4 + kt) * 64 + lane) * 8) = ll;   // frag 4+kt   (low)

  // diag = ||row||^2 : lanes l and l^32 hold the two 8-slices of ktile kt
  p += __shfl_xor(p, 32);
  __shared__ float ds[4][32];
  if (lane < 32) ds[kt][lane] = p;
  __syncthreads();
  if (threadIdx.x < 32)
    diag[mat * NS + tile * 32 + threadIdx.x] =
        ds[0][threadIdx.x] + ds[1][threadIdx.x] +
        ds[2][threadIdx.x] + ds[3][threadIdx.x];
}

// ---------------------------------------------------------------------------
// Main v6: SYMMETRIC Gram — only tile-pairs J >= I computed (halves MFMA
// and B-traffic; exp count unchanged). Block = (mat, Ig, Jc): I-strip of 4
// tiles (one per wave), J-chunk of 16 tiles staged via R5-proven LDS double
// buffer (one barrier per jt). Per processed pair:
//   acc[r,lane] = E_I[crow(r,hf)] . E_J[lane&31]        (12 MFMA, acc=0 init)
//   A-side (rows of I): rs[r] += exp2(fma(acc, C, -d_I[crow]*C))
//   B-side (rows of J, skipped when J==I):
//     cs = sum_r exp2(fma(acc, C, -d_J[lane&31]*C))     (in-lane tree)
//     cs += shfl_xor(cs,32);  lane<32: atomicAdd(accum[J*32+lane], cs)
// A-side flushed once per chunk via atomicAdd. Empty blocks exit early.
// Waves with J < myI skip compute but keep barriers (wave-uniform branch).
// ---------------------------------------------------------------------------
__global__ __launch_bounds__(256) void ssm_mfma_kernel(
    const _Float16* __restrict__ Efrag, const float* __restrict__ diag,
    float* __restrict__ accum) {
  int b = blockIdx.x;
  int jc  = b & (NJC - 1);
  int ig  = (b >> 4) & 63;
  int mat = b >> 10;
  if (jc * 16 + 15 < ig * 4) return;       // entire J-chunk below I-strip

  int wave = threadIdx.x >> 6;
  int lane = threadIdx.x & 63;
  int hf   = lane >> 5;
  int myI  = ig * 4 + wave;                // this wave's I-tile
  const _Float16* Em = Efrag + (size_t)mat * NTILE * 4096;

  // A fragments (frags 0..3 = h ktiles, 4..7 = l ktiles)
  half8 a[8];
  #pragma unroll
  for (int f = 0; f < 8; ++f)
    a[f] = *(const half8*)(Em + (size_t)myI * 4096 + (f * 64 + lane) * 8);

  // A-side shift: -d_I[crow(r,hf)] * C
  float negdIC[16];
  #pragma unroll
  for (int r = 0; r < 16; ++r)
    negdIC[r] = -diag[mat * NS + myI * 32 +
                      (r & 3) + 8 * (r >> 2) + 4 * hf] * C_L2E_TAU;

  float rs[16];
  #pragma unroll
  for (int r = 0; r < 16; ++r) rs[r] = 0.f;

  __shared__ __align__(16) _Float16 Bbuf[2][4096];   // 2 x 8KB double buffer

  int J0 = jc * JT_PER_CHUNK;
  auto stage = [&](int buf, int jt) {
    const char* src = (const char*)(Em + (size_t)(J0 + jt) * 4096) + wave * 2048;
    char* dst = (char*)&Bbuf[buf][0] + wave * 2048;
    GLDS16(src + lane * 16, dst);
    GLDS16(src + 1024 + lane * 16, dst + 1024);
  };

  stage(0, 0);
  __syncthreads();   // drains vmcnt before first use

  for (int jt = 0; jt < JT_PER_CHUNK; ++jt) {
    int cur = jt & 1;
    if (jt + 1 < JT_PER_CHUNK) stage(cur ^ 1, jt + 1);

    int J = J0 + jt;
    if (J >= myI) {                        // wave-uniform branch
      // B-side shift for this J (per-lane): issue load early
      float negdJC = -diag[mat * NS + J * 32 + (lane & 31)] * C_L2E_TAU;

      half8 bh[4], bl[4];
      #pragma unroll
      for (int k = 0; k < 4; ++k) {
        bh[k] = *(const half8*)(&Bbuf[cur][0] + ((k)     * 64 + lane) * 8);
        bl[k] = *(const half8*)(&Bbuf[cur][0] + ((4 + k) * 64 + lane) * 8);
      }

      f32x16 acc = {0.f,0.f,0.f,0.f,0.f,0.f,0.f,0.f,
                    0.f,0.f,0.f,0.f,0.f,0.f,0.f,0.f};
      #pragma unroll
      for (int k = 0; k < 4; ++k)
        acc = __builtin_amdgcn_mfma_f32_32x32x16_f16(a[k], bh[k], acc, 0, 0, 0);
      #pragma unroll
      for (int k = 0; k < 4; ++k)
        acc = __builtin_amdgcn_mfma_f32_32x32x16_f16(a[k], bl[k], acc, 0, 0, 0);
      #pragma unroll
      for (int k = 0; k < 4; ++k)
        acc = __builtin_amdgcn_mfma_f32_32x32x16_f16(a[4 + k], bh[k], acc, 0, 0, 0);

      // A-side: rows of I
      #pragma unroll
      for (int r = 0; r < 16; ++r)
        rs[r] += exp2_raw(fmaf(acc[r], C_L2E_TAU, negdIC[r]));

      // B-side: rows of J (strictly above diagonal)
      if (J > myI) {
        float cs = 0.f;
        #pragma unroll
        for (int r = 0; r < 16; ++r)
          cs += exp2_raw(fmaf(acc[r], C_L2E_TAU, negdJC));
        cs += __shfl_xor(cs, 32);          // combine complementary row-halves
        if (lane < 32)
          atomicAdd(&accum[mat * NS + J * 32 + lane], cs);
      }
    }
    __syncthreads();   // Bbuf[cur] reads done; next stage may overwrite
  }

  // A-side flush: reduce rs across the 32 lanes of each half, atomic once
  #pragma unroll
  for (int r = 0; r < 16; ++r) {
    float v = rs[r];
    #pragma unroll
    for (int off = 16; off; off >>= 1) v += __shfl_xor(v, off);
    if ((lane & 31) == 0)
      atomicAdd(&accum[mat * NS + myI * 32 +
                       (r & 3) + 8 * (r >> 2) + 4 * hf], v);
  }
}

// ---------------------------------------------------------------------------
// Finalize (single block of 1024): accum already holds full per-row exp sums.
// out[0] = loss_u + loss_i, out[1] = loss_u, out[2] = loss_i
// ---------------------------------------------------------------------------
__global__ __launch_bounds__(1024) void finalize_kernel(
    const float* __restrict__ accum, float* __restrict__ out) {
  float lu = 0.f, li = 0.f;
  for (int r = threadIdx.x; r < 2 * NS; r += 1024) {
    float l = logf(accum[r]);
    if (r < NS) lu += l; else li += l;
  }
  #pragma unroll
  for (int off = 32; off; off >>= 1) {
    lu += __shfl_down(lu, off);
    li += __shfl_down(li, off);
  }
  __shared__ float red[2][16];
  int wave = threadIdx.x >> 6;
  if ((threadIdx.x & 63) == 0) { red[0][wave] = lu; red[1][wave] = li; }
  __syncthreads();
  if (threadIdx.x == 0) {
    float su = 0.f, si = 0.f;
    #pragma unroll
    for (int w = 0; w < 16; ++w) { su += red[0][w]; si += red[1][w]; }
    su *= (1.0f / NS);
    si *= (1.0f / NS);
    out[0] = su + si;
    out[1] = su;
    out[2] = si;
  }
}

// ---------------------------------------------------------------------------
// ws: Efrag 4MB | diag 64KB | accum 64KB   (~4.13MB, smallest footprint yet)
// accum zeroed by prep every launch (harness re-poisons ws).
// ---------------------------------------------------------------------------
extern "C" void kernel_launch(void* const* d_in, const int* in_sizes, int n_in,
                              void* d_out, int out_size, void* d_ws, size_t ws_size,
                              hipStream_t stream) {
  const float* users = (const float*)d_in[0];
  const float* items = (const float*)d_in[1];
  const int*   uidx  = (const int*)d_in[2];
  const int*   iidx  = (const int*)d_in[3];
  float* out = (float*)d_out;

  _Float16* Efrag = (_Float16*)d_ws;                         // 2*256*4096 f16 = 4MB
  float* diag     = (float*)((char*)d_ws + (size_t)4194304); // 16384 f32
  float* accum    = diag + 2 * NS;                           // 16384 f32

  prep_kernel<<<2 * NTILE, 256, 0, stream>>>(users, items, uidx, iidx,
                                             Efrag, diag, accum);
  ssm_mfma_kernel<<<2 * 64 * NJC, 256, 0, stream>>>(Efrag, diag, accum);
  finalize_kernel<<<1, 1024, 0, stream>>>(accum, out);
}